// Round 4
// baseline (362.563 us; speedup 1.0000x reference)
//
#include <hip/hip_runtime.h>
#include <stdint.h>

#pragma clang fp contract(off)

#define BB 16
#define NN 25200
#define ROW 85
#define NCLS 80
#define TK 2048
#define SORTN 4096
#define NBIN 4096
#define MAXDET 1000
#define CONF 0.25f
#define IOUT 0.45f
#define SROWS 64

typedef float fvec4 __attribute__((ext_vector_type(4)));

#define AS1 __attribute__((address_space(1)))
#define AS3 __attribute__((address_space(3)))

// ---------------- K1: coalesced LDS staging + scores + argmax + histogram ----------------
__global__ __launch_bounds__(128) void score_kernel(const float* __restrict__ pred,
                                                    float* __restrict__ scores,
                                                    uint8_t* __restrict__ cls,
                                                    unsigned int* __restrict__ hist) {
  __shared__ __align__(16) float srow[SROWS * ROW];  // 21760 B
  const int tile = blockIdx.x;
  const int b = blockIdx.y;
  const int tid = threadIdx.x;
  const int lane = tid & 63;
  const int row0 = tile * SROWS;
  int nrows = NN - row0;
  if (nrows > SROWS) nrows = SROWS;
  const char* gsrc = (const char*)(pred + ((size_t)b * NN + row0) * ROW);
  const int nbytes = nrows * ROW * 4;  // multiple of 16
  for (int off = tid * 16; off < nbytes; off += 128 * 16) {
    __builtin_amdgcn_global_load_lds((AS1 void*)(gsrc + off),
                                     (AS3 void*)((char*)srow + (off - lane * 16)),
                                     16, 0, 0);
  }
  __builtin_amdgcn_s_waitcnt(0);
  __syncthreads();
  if (tid < nrows) {
    const int n = row0 + tid;
    const float* r = srow + tid * ROW;   // stride 85 dwords -> 2-way bank alias (free)
    float obj = r[4];
    float best = r[5];
    int bid = 0;
#pragma unroll
    for (int c = 1; c < NCLS; ++c) {
      float p = r[5 + c];
      if (p > best) { best = p; bid = c; }   // strict > keeps first max (tie rule)
    }
    float score = obj * best;
    bool valid = (obj > CONF) && (score > CONF);
    float sout = valid ? score : 0.0f;
    scores[(size_t)b * NN + n] = sout;
    cls[(size_t)b * NN + n] = (uint8_t)bid;
    if (valid) {
      unsigned int u = __float_as_uint(sout);        // in (0x3E800000, 0x3F800000)
      unsigned int bin = (u - 0x3E800001u) >> 12;
      if (bin > NBIN - 1) bin = NBIN - 1;
      atomicAdd(&hist[(size_t)b * NBIN + bin], 1u);
    }
  }
}

// ---------------- K2: per-batch suffix scan of hist -> gsoff, pivot P, total ----------------
__global__ __launch_bounds__(256) void scan_kernel(const unsigned int* __restrict__ hist,
                                                   unsigned int* __restrict__ gsoff,
                                                   int* __restrict__ gP,
                                                   int* __restrict__ gtot) {
  const int b = blockIdx.x;
  const int t = threadIdx.x;
  const int w = t >> 6, lane = t & 63;
  const unsigned int* h = hist + (size_t)b * NBIN;
  unsigned int loc[16];
  int ssum = 0;
#pragma unroll
  for (int k = 0; k < 16; ++k) {
    loc[k] = h[NBIN - 1 - (16 * t + k)];   // descending bins
    ssum += (int)loc[k];
  }
  // wave-level inclusive scan of per-thread sums
  int v = ssum;
  for (int o = 1; o < 64; o <<= 1) { int u = __shfl_up(v, o); if (lane >= o) v += u; }
  __shared__ int sw[4];
  __shared__ int sfound;
  if (t == 0) sfound = 0;
  if (lane == 63) sw[w] = v;
  __syncthreads();
  int wbase = 0;
  for (int i = 0; i < w; ++i) wbase += sw[i];
  const int total = sw[0] + sw[1] + sw[2] + sw[3];
  int run = wbase + v - ssum;   // exclusive suffix-sum at this thread's first bin
#pragma unroll
  for (int k = 0; k < 16; ++k) {
    int bin = NBIN - 1 - (16 * t + k);
    gsoff[(size_t)b * NBIN + bin] = (unsigned int)run;
    int c = (int)loc[k];
    if (run < TK && run + c >= TK) {   // unique bin satisfies this
      gP[b] = bin;
      gtot[b] = run + c;
      sfound = 1;
    }
    run += c;
  }
  __syncthreads();
  if (t == 0 && !sfound) { gP[b] = 0; gtot[b] = total; }  // < TK valid (never here)
}

// ---------------- K3: multi-block scatter to exact bin segments (global atomics) ----------------
__global__ __launch_bounds__(1024) void scatter_kernel(const float* __restrict__ scores,
                                                       const unsigned int* __restrict__ gsoff,
                                                       const int* __restrict__ gP,
                                                       unsigned int* __restrict__ gcnt,
                                                       unsigned long long* __restrict__ gskey) {
  const int b = blockIdx.y;
  const int n = blockIdx.x * 1024 + threadIdx.x;
  if (n >= NN) return;
  const unsigned int P = (unsigned int)gP[b];
  unsigned int u = __float_as_uint(scores[(size_t)b * NN + n]);
  if (u > 0x3E800000u) {
    unsigned int bin = (u - 0x3E800001u) >> 12;
    if (bin > NBIN - 1) bin = NBIN - 1;
    if (bin >= P) {
      unsigned int pos = gsoff[(size_t)b * NBIN + bin] +
                         atomicAdd(&gcnt[(size_t)b * NBIN + bin], 1u);
      if (pos < SORTN)
        gskey[(size_t)b * SORTN + pos] = ((unsigned long long)u << 32) | (unsigned int)(~n);
    }
  }
}

// ---------------- K4: bin-per-lane metadata + wave-cooperative rank-sort + emit ----------------
__device__ __forceinline__ void emit_one(const float* __restrict__ pred,
                                         const uint8_t* __restrict__ cls,
                                         int b, int pos, unsigned long long key,
                                         float* __restrict__ gtops,
                                         fvec4* __restrict__ gbox,
                                         int* __restrict__ gcls) {
  int idx = (int)(~(unsigned int)key);
  gtops[(size_t)b * TK + pos] = __uint_as_float((unsigned int)(key >> 32));
  gcls[(size_t)b * TK + pos] = (int)cls[(size_t)b * NN + idx];
  const float* rowp = pred + ((size_t)b * NN + idx) * ROW;
  float cx = rowp[0], cy = rowp[1], w2 = rowp[2], h2 = rowp[3];
  float hw = w2 * 0.5f, hh = h2 * 0.5f;
  fvec4 bb4;
  bb4[0] = cx - hw; bb4[1] = cy - hh; bb4[2] = cx + hw; bb4[3] = cy + hh;
  gbox[(size_t)b * TK + pos] = bb4;
}

__global__ __launch_bounds__(256) void binsort_kernel(const float* __restrict__ pred,
                                                      const uint8_t* __restrict__ cls,
                                                      const unsigned int* __restrict__ gsoff,
                                                      const unsigned int* __restrict__ gcnt,
                                                      const unsigned long long* __restrict__ gskey,
                                                      float* __restrict__ gtops,
                                                      fvec4* __restrict__ gbox,
                                                      int* __restrict__ gcls) {
  const int b = blockIdx.y;
  const int w = threadIdx.x >> 6;
  const int lane = threadIdx.x & 63;
  const int mybin = (blockIdx.x * 4 + w) * 64 + lane;   // 16 blocks x 4 waves x 64 = 4096 bins
  // coalesced metadata loads: one lane = one bin (no serial pointer-chase)
  int s = (int)gcnt[(size_t)b * NBIN + mybin];
  int base = (int)gsoff[(size_t)b * NBIN + mybin];
  bool act = (s > 0) && (base < TK);    // bins with base >= TK can never emit
  unsigned long long mset = __ballot(act);
  while (mset) {
    int l = (int)(__ffsll((long long)mset) - 1);
    mset &= mset - 1;
    int s_l = __shfl(s, l);
    int base_l = __shfl(base, l);
    if (base_l + s_l > SORTN) s_l = SORTN - base_l;   // keys beyond SORTN were never written
    const unsigned long long* seg = gskey + (size_t)b * SORTN + base_l;
    // lane-strided exact rank-count: keys unique -> rank is a bijection; works for any s
    for (int i = lane; i < s_l; i += 64) {
      unsigned long long ki = seg[i];
      int rank = 0;
      for (int j = 0; j < s_l; ++j) rank += (seg[j] > ki) ? 1 : 0;   // L1-resident re-reads
      int pos = base_l + rank;
      if (pos < TK) emit_one(pred, cls, b, pos, ki, gtops, gbox, gcls);
    }
  }
}

// ---------------- K5: per-class compact + register NMS + output compaction ----------------
__global__ __launch_bounds__(1024) void final_kernel(const float* __restrict__ gtops,
                                                     const fvec4* __restrict__ gbox,
                                                     const int* __restrict__ gcls,
                                                     const int* __restrict__ gtot,
                                                     float* __restrict__ out) {
  const int b = blockIdx.x;
  const int t = threadIdx.x;
  const int w = t >> 6;
  const int lane = t & 63;
  __shared__ float sx1[TK], sy1[TK], sx2[TK], sy2[TK];  // 32 KB
  __shared__ float stop[TK];                            // 8 KB
  __shared__ unsigned short scls[TK];                   // 4 KB (0xFFFF = pad)
  __shared__ unsigned short cgrpL[TK];                  // 4 KB
  __shared__ unsigned char skp[TK];                     // 2 KB
  __shared__ int ccnt[NCLS];
  __shared__ int coffs[NCLS + 1];
  __shared__ int swsum[16];

  int npos = gtot[b];
  if (npos > TK) npos = TK;
  for (int i = t; i < TK; i += 1024) {
    if (i < npos) {
      fvec4 bb4 = gbox[(size_t)b * TK + i];
      sx1[i] = bb4[0]; sy1[i] = bb4[1]; sx2[i] = bb4[2]; sy2[i] = bb4[3];
      stop[i] = gtops[(size_t)b * TK + i];
      scls[i] = (unsigned short)gcls[(size_t)b * TK + i];
      skp[i] = 1;
    } else {
      sx1[i] = 0.f; sy1[i] = 0.f; sx2[i] = 0.f; sy2[i] = 0.f;
      stop[i] = 0.f;
      scls[i] = (unsigned short)0xFFFFu;
      skp[i] = 0;
    }
  }
  __syncthreads();

  // ---- stable per-class compaction: wave w handles classes w, w+16, ... ----
#pragma unroll
  for (int k = 0; k < 5; ++k) {
    int c = w + 16 * k;
    int cnt = 0;
    for (int base2 = 0; base2 < TK; base2 += 64) {
      bool match = ((int)scls[base2 + lane] == c);
      cnt += (int)__popcll(__ballot(match));
    }
    if (lane == 0) ccnt[c] = cnt;
  }
  __syncthreads();
  if (t == 0) {
    int r2 = 0;
    for (int c = 0; c < NCLS; ++c) { coffs[c] = r2; r2 += ccnt[c]; }
    coffs[NCLS] = r2;
  }
  __syncthreads();
#pragma unroll
  for (int k = 0; k < 5; ++k) {
    int c = w + 16 * k;
    int run2 = coffs[c];
    for (int base2 = 0; base2 < TK; base2 += 64) {
      bool match = ((int)scls[base2 + lane] == c);
      unsigned long long bal = __ballot(match);
      int r3 = (int)__popcll(bal & ((1ull << lane) - 1ull));
      if (match) cgrpL[run2 + r3] = (unsigned short)(base2 + lane);
      run2 += (int)__popcll(bal);
    }
  }
  __syncthreads();

  // ---- per-class greedy NMS, register-resident (classes never cross-suppress) ----
  for (int k = 0; k < 5; ++k) {
    int c = w + 16 * k;
    int start = coffs[c];
    int m = coffs[c + 1] - start;
    if (m <= 0) continue;
    int nq = (m + 63) >> 6;
    unsigned int km = 0;
    for (int q = 0; q < nq; ++q)
      if (lane + (q << 6) < m) km |= (1u << q);
    float b0x1 = 0.f, b0y1 = 0.f, b0x2 = 0.f, b0y2 = 0.f;
    if (lane < m) {
      int e0 = cgrpL[start + lane];
      b0x1 = sx1[e0]; b0y1 = sy1[e0]; b0x2 = sx2[e0]; b0y2 = sy2[e0];
    }
    for (int i = 0; i < m; ++i) {
      int q = i >> 6;
      unsigned int kmi = __shfl(km, i & 63);
      if (!((kmi >> q) & 1u)) continue;   // suppressed pivot: uniform skip
      float ax1, ay1, ax2, ay2;
      if (q == 0) {
        ax1 = __shfl(b0x1, i); ay1 = __shfl(b0y1, i);
        ax2 = __shfl(b0x2, i); ay2 = __shfl(b0y2, i);
      } else {
        int ei = cgrpL[start + i];
        ax1 = sx1[ei]; ay1 = sy1[ei]; ax2 = sx2[ei]; ay2 = sy2[ei];
      }
      float aarea = (ax2 - ax1) * (ay2 - ay1);
      if ((km & 1u) && lane > i) {
        float ltx = fmaxf(ax1, b0x1), lty = fmaxf(ay1, b0y1);
        float rbx = fminf(ax2, b0x2), rby = fminf(ay2, b0y2);
        float iw = fmaxf(rbx - ltx, 0.0f);
        float ih = fmaxf(rby - lty, 0.0f);
        float inter = iw * ih;
        float barea = (b0x2 - b0x1) * (b0y2 - b0y1);
        float iou = inter / (aarea + barea - inter + 1e-7f);
        if (iou > IOUT) km &= ~1u;
      }
      for (int q2 = 1; q2 < nq; ++q2) {
        int j = lane + (q2 << 6);
        if (((km >> q2) & 1u) && j > i && j < m) {
          int ej = cgrpL[start + j];
          float jx1 = sx1[ej], jy1 = sy1[ej], jx2 = sx2[ej], jy2 = sy2[ej];
          float ltx = fmaxf(ax1, jx1), lty = fmaxf(ay1, jy1);
          float rbx = fminf(ax2, jx2), rby = fminf(ay2, jy2);
          float iw = fmaxf(rbx - ltx, 0.0f);
          float ih = fmaxf(rby - lty, 0.0f);
          float inter = iw * ih;
          float barea = (jx2 - jx1) * (jy2 - jy1);
          float iou = inter / (aarea + barea - inter + 1e-7f);
          if (iou > IOUT) km &= ~(1u << q2);
        }
      }
    }
    for (int q = 0; q < nq; ++q) {
      int j = lane + (q << 6);
      if (j < m) skp[cgrpL[start + j]] = (unsigned char)((km >> q) & 1u);
    }
  }
  __syncthreads();

  // ---- output compaction (shfl-based scan, 3 barriers) ----
  int kp0 = (int)skp[2 * t];
  int kp1 = (int)skp[2 * t + 1];
  int cnt2 = kp0 + kp1;
  int v2 = cnt2;
  for (int o = 1; o < 64; o <<= 1) { int u2 = __shfl_up(v2, o); if (lane >= o) v2 += u2; }
  if (lane == 63) swsum[w] = v2;
  __syncthreads();
  if (w == 0) {
    int x = (lane < 16) ? swsum[lane] : 0;
    for (int o = 1; o < 16; o <<= 1) { int u2 = __shfl_up(x, o); if (lane >= o) x += u2; }
    if (lane < 16) swsum[lane] = x;   // inclusive wave sums
  }
  __syncthreads();
  int r4 = (w ? swsum[w - 1] : 0) + v2 - cnt2;
  int K = swsum[15];
#pragma unroll
  for (int k = 0; k < 2; ++k) {
    int kp = (k == 0) ? kp0 : kp1;
    if (kp) {
      if (r4 < MAXDET) {
        int j = 2 * t + k;
        float* o = out + ((size_t)b * MAXDET + r4) * 6;
        o[0] = sx1[j]; o[1] = sy1[j]; o[2] = sx2[j]; o[3] = sy2[j];
        o[4] = stop[j];
        o[5] = (float)scls[j];
      }
      ++r4;
    }
  }
  int Kc = K < MAXDET ? K : MAXDET;
  for (int r2 = Kc + t; r2 < MAXDET; r2 += 1024) {
    float* o = out + ((size_t)b * MAXDET + r2) * 6;
    o[0] = 0.0f; o[1] = 0.0f; o[2] = 0.0f; o[3] = 0.0f; o[4] = 0.0f; o[5] = -1.0f;
  }
}

extern "C" void kernel_launch(void* const* d_in, const int* in_sizes, int n_in,
                              void* d_out, int out_size, void* d_ws, size_t ws_size,
                              hipStream_t stream) {
  const float* pred = (const float*)d_in[0];
  float* out = (float*)d_out;

  char* ws = (char*)d_ws;
  size_t off = 0;
  float*              scores = (float*)(ws + off);              off += (size_t)BB * NN * 4;
  uint8_t*            cls    = (uint8_t*)(ws + off);            off += (size_t)BB * NN;
  off = (off + 255) & ~(size_t)255;
  unsigned int*       hist   = (unsigned int*)(ws + off);       off += (size_t)BB * NBIN * 4;
  unsigned int*       gcnt   = (unsigned int*)(ws + off);       off += (size_t)BB * NBIN * 4;
  unsigned int*       gsoff  = (unsigned int*)(ws + off);       off += (size_t)BB * NBIN * 4;
  unsigned long long* gskey  = (unsigned long long*)(ws + off); off += (size_t)BB * SORTN * 8;
  float*              gtops  = (float*)(ws + off);              off += (size_t)BB * TK * 4;
  fvec4*              gbox   = (fvec4*)(ws + off);              off += (size_t)BB * TK * 16;
  int*                gcls   = (int*)(ws + off);                off += (size_t)BB * TK * 4;
  int*                gP     = (int*)(ws + off);                off += (size_t)BB * 4;
  int*                gtot   = (int*)(ws + off);                off += (size_t)BB * 4;
  (void)ws_size; (void)in_sizes; (void)n_in; (void)out_size;

  // hist + gcnt are adjacent: one memset clears both
  hipMemsetAsync(hist, 0, (size_t)BB * NBIN * 4 * 2, stream);
  score_kernel<<<dim3((NN + SROWS - 1) / SROWS, BB), 128, 0, stream>>>(pred, scores, cls, hist);
  scan_kernel<<<BB, 256, 0, stream>>>(hist, gsoff, gP, gtot);
  scatter_kernel<<<dim3((NN + 1023) / 1024, BB), 1024, 0, stream>>>(scores, gsoff, gP, gcnt, gskey);
  binsort_kernel<<<dim3(16, BB), 256, 0, stream>>>(pred, cls, gsoff, gcnt, gskey,
                                                   gtops, gbox, gcls);
  final_kernel<<<BB, 1024, 0, stream>>>(gtops, gbox, gcls, gtot, out);
}

// Round 5
// 278.455 us; speedup vs baseline: 1.3021x; 1.3021x over previous
//
#include <hip/hip_runtime.h>
#include <stdint.h>

#pragma clang fp contract(off)

#define BB 16
#define NN 25200
#define ROW 85
#define NCLS 80
#define TK 2048
#define SORTN 4096
#define NBIN 4096
#define MAXDET 1000
#define CONF 0.25f
#define IOUT 0.45f
#define SROWS 64

typedef float fvec4 __attribute__((ext_vector_type(4)));

#define AS1 __attribute__((address_space(1)))
#define AS3 __attribute__((address_space(3)))

// ---------------- K1: coalesced LDS staging + scores + argmax + histogram ----------------
__global__ __launch_bounds__(128) void score_kernel(const float* __restrict__ pred,
                                                    float* __restrict__ scores,
                                                    uint8_t* __restrict__ cls,
                                                    unsigned int* __restrict__ hist) {
  __shared__ __align__(16) float srow[SROWS * ROW];  // 21760 B
  const int tile = blockIdx.x;
  const int b = blockIdx.y;
  const int tid = threadIdx.x;
  const int lane = tid & 63;
  const int row0 = tile * SROWS;
  int nrows = NN - row0;
  if (nrows > SROWS) nrows = SROWS;
  const char* gsrc = (const char*)(pred + ((size_t)b * NN + row0) * ROW);
  const int nbytes = nrows * ROW * 4;  // multiple of 16
  for (int off = tid * 16; off < nbytes; off += 128 * 16) {
    __builtin_amdgcn_global_load_lds((AS1 void*)(gsrc + off),
                                     (AS3 void*)((char*)srow + (off - lane * 16)),
                                     16, 0, 0);
  }
  __builtin_amdgcn_s_waitcnt(0);
  __syncthreads();
  if (tid < nrows) {
    const int n = row0 + tid;
    const float* r = srow + tid * ROW;   // stride 85 dwords -> 2-way bank alias (free)
    float obj = r[4];
    float best = r[5];
    int bid = 0;
#pragma unroll
    for (int c = 1; c < NCLS; ++c) {
      float p = r[5 + c];
      if (p > best) { best = p; bid = c; }   // strict > keeps first max (tie rule)
    }
    float score = obj * best;
    bool valid = (obj > CONF) && (score > CONF);
    float sout = valid ? score : 0.0f;
    scores[(size_t)b * NN + n] = sout;
    cls[(size_t)b * NN + n] = (uint8_t)bid;
    if (valid) {
      unsigned int u = __float_as_uint(sout);        // in (0x3E800000, 0x3F800000)
      unsigned int bin = (u - 0x3E800001u) >> 12;
      if (bin > NBIN - 1) bin = NBIN - 1;
      atomicAdd(&hist[(size_t)b * NBIN + bin], 1u);
    }
  }
}

// ---------------- K2: per-batch suffix scan of hist -> gsoff, pivot P, total ----------------
__global__ __launch_bounds__(256) void scan_kernel(const unsigned int* __restrict__ hist,
                                                   unsigned int* __restrict__ gsoff,
                                                   int* __restrict__ gP,
                                                   int* __restrict__ gtot) {
  const int b = blockIdx.x;
  const int t = threadIdx.x;
  const int w = t >> 6, lane = t & 63;
  const unsigned int* h = hist + (size_t)b * NBIN;
  unsigned int loc[16];
  int ssum = 0;
#pragma unroll
  for (int k = 0; k < 16; ++k) {
    loc[k] = h[NBIN - 1 - (16 * t + k)];   // descending bins
    ssum += (int)loc[k];
  }
  // wave-level inclusive scan of per-thread sums
  int v = ssum;
  for (int o = 1; o < 64; o <<= 1) { int u = __shfl_up(v, o); if (lane >= o) v += u; }
  __shared__ int sw[4];
  __shared__ int sfound;
  if (t == 0) sfound = 0;
  if (lane == 63) sw[w] = v;
  __syncthreads();
  int wbase = 0;
  for (int i = 0; i < w; ++i) wbase += sw[i];
  const int total = sw[0] + sw[1] + sw[2] + sw[3];
  int run = wbase + v - ssum;   // exclusive suffix-sum at this thread's first bin
#pragma unroll
  for (int k = 0; k < 16; ++k) {
    int bin = NBIN - 1 - (16 * t + k);
    gsoff[(size_t)b * NBIN + bin] = (unsigned int)run;
    int c = (int)loc[k];
    if (run < TK && run + c >= TK) {   // unique bin satisfies this
      gP[b] = bin;
      gtot[b] = run + c;
      sfound = 1;
    }
    run += c;
  }
  __syncthreads();
  if (t == 0 && !sfound) { gP[b] = 0; gtot[b] = total; }  // < TK valid (never here)
}

// ---------------- K3: multi-block scatter to exact bin segments (global atomics) ----------------
__global__ __launch_bounds__(1024) void scatter_kernel(const float* __restrict__ scores,
                                                       const unsigned int* __restrict__ gsoff,
                                                       const int* __restrict__ gP,
                                                       unsigned int* __restrict__ gcnt,
                                                       unsigned long long* __restrict__ gskey) {
  const int b = blockIdx.y;
  const int n = blockIdx.x * 1024 + threadIdx.x;
  if (n >= NN) return;
  const unsigned int P = (unsigned int)gP[b];
  unsigned int u = __float_as_uint(scores[(size_t)b * NN + n]);
  if (u > 0x3E800000u) {
    unsigned int bin = (u - 0x3E800001u) >> 12;
    if (bin > NBIN - 1) bin = NBIN - 1;
    if (bin >= P) {
      unsigned int pos = gsoff[(size_t)b * NBIN + bin] +
                         atomicAdd(&gcnt[(size_t)b * NBIN + bin], 1u);
      if (pos < SORTN)
        gskey[(size_t)b * SORTN + pos] = ((unsigned long long)u << 32) | (unsigned int)(~n);
    }
  }
}

// ---------------- K4: rank+emit (thread-per-candidate, LDS-resident) +
//                  per-class compact + register NMS + output compaction ----------------
__global__ __launch_bounds__(1024) void final_kernel(const float* __restrict__ pred,
                                                     const uint8_t* __restrict__ cls,
                                                     const unsigned int* __restrict__ gsoff,
                                                     const unsigned int* __restrict__ gcnt,
                                                     const unsigned long long* __restrict__ gskey,
                                                     const int* __restrict__ gtot,
                                                     float* __restrict__ out) {
  const int b = blockIdx.x;
  const int t = threadIdx.x;
  const int w = t >> 6;
  const int lane = t & 63;
  __shared__ unsigned long long skey[SORTN];            // 32 KB scattered keys
  __shared__ float sx1[TK], sy1[TK], sx2[TK], sy2[TK];  // 32 KB boxes (xyxy)
  __shared__ float stop[TK];                            // 8 KB scores
  __shared__ unsigned short scls[TK];                   // 4 KB (0xFFFF = pad)
  __shared__ unsigned short cgrpL[TK];                  // 4 KB per-class lists
  __shared__ unsigned char skp[TK];                     // 2 KB keep flags
  __shared__ int ccnt[NCLS];
  __shared__ int coffs[NCLS + 1];
  __shared__ int swsum[16];

  int total = gtot[b];
  int used = total < SORTN ? total : SORTN;   // all scattered keys live in [0, used)
  int npos = total < TK ? total : TK;

  // ---- load keys + init padding slots ----
  for (int i = t; i < used; i += 1024) skey[i] = gskey[(size_t)b * SORTN + i];
  for (int i = t; i < TK; i += 1024) {
    if (i >= npos) {
      sx1[i] = 0.f; sy1[i] = 0.f; sx2[i] = 0.f; sy2[i] = 0.f;
      stop[i] = 0.f;
      scls[i] = (unsigned short)0xFFFFu;
      skp[i] = 0;
    }
  }
  __syncthreads();

  // ---- rank-by-count + direct emit: one thread per candidate ----
  // rank within bin segment is a bijection (keys unique) -> every q < npos filled once.
  for (int p = t; p < used; p += 1024) {
    unsigned long long k = skey[p];
    unsigned int u = (unsigned int)(k >> 32);
    unsigned int bin = (u - 0x3E800001u) >> 12;
    if (bin > NBIN - 1) bin = NBIN - 1;
    int base = (int)gsoff[(size_t)b * NBIN + bin];
    int cnt = (int)gcnt[(size_t)b * NBIN + bin];
    if (base + cnt > used) cnt = used - base;   // safety
    int rank = 0;
    for (int j = 0; j < cnt; ++j) rank += (skey[base + j] > k) ? 1 : 0;  // LDS scan, avg ~6
    int q = base + rank;
    if (q < npos) {
      int idx = (int)(~(unsigned int)k);
      stop[q] = __uint_as_float(u);
      scls[q] = (unsigned short)cls[(size_t)b * NN + idx];
      skp[q] = 1;
      const float* rowp = pred + ((size_t)b * NN + idx) * ROW;
      float cx = rowp[0], cy = rowp[1], w2 = rowp[2], h2 = rowp[3];
      float hw = w2 * 0.5f, hh = h2 * 0.5f;
      sx1[q] = cx - hw; sy1[q] = cy - hh; sx2[q] = cx + hw; sy2[q] = cy + hh;
    }
  }
  __syncthreads();

  // ---- stable per-class compaction: wave w handles classes w, w+16, ... ----
#pragma unroll
  for (int k = 0; k < 5; ++k) {
    int c = w + 16 * k;
    int cnt = 0;
    for (int base2 = 0; base2 < TK; base2 += 64) {
      bool match = ((int)scls[base2 + lane] == c);
      cnt += (int)__popcll(__ballot(match));
    }
    if (lane == 0) ccnt[c] = cnt;
  }
  __syncthreads();
  if (t == 0) {
    int r2 = 0;
    for (int c = 0; c < NCLS; ++c) { coffs[c] = r2; r2 += ccnt[c]; }
    coffs[NCLS] = r2;
  }
  __syncthreads();
#pragma unroll
  for (int k = 0; k < 5; ++k) {
    int c = w + 16 * k;
    int run2 = coffs[c];
    for (int base2 = 0; base2 < TK; base2 += 64) {
      bool match = ((int)scls[base2 + lane] == c);
      unsigned long long bal = __ballot(match);
      int r3 = (int)__popcll(bal & ((1ull << lane) - 1ull));
      if (match) cgrpL[run2 + r3] = (unsigned short)(base2 + lane);
      run2 += (int)__popcll(bal);
    }
  }
  __syncthreads();

  // ---- per-class greedy NMS, register-resident (classes never cross-suppress) ----
  for (int k = 0; k < 5; ++k) {
    int c = w + 16 * k;
    int start = coffs[c];
    int m = coffs[c + 1] - start;
    if (m <= 0) continue;
    int nq = (m + 63) >> 6;
    unsigned int km = 0;
    for (int q = 0; q < nq; ++q)
      if (lane + (q << 6) < m) km |= (1u << q);
    float b0x1 = 0.f, b0y1 = 0.f, b0x2 = 0.f, b0y2 = 0.f;
    if (lane < m) {
      int e0 = cgrpL[start + lane];
      b0x1 = sx1[e0]; b0y1 = sy1[e0]; b0x2 = sx2[e0]; b0y2 = sy2[e0];
    }
    for (int i = 0; i < m; ++i) {
      int q = i >> 6;
      unsigned int kmi = __shfl(km, i & 63);
      if (!((kmi >> q) & 1u)) continue;   // suppressed pivot: uniform skip
      float ax1, ay1, ax2, ay2;
      if (q == 0) {
        ax1 = __shfl(b0x1, i); ay1 = __shfl(b0y1, i);
        ax2 = __shfl(b0x2, i); ay2 = __shfl(b0y2, i);
      } else {
        int ei = cgrpL[start + i];
        ax1 = sx1[ei]; ay1 = sy1[ei]; ax2 = sx2[ei]; ay2 = sy2[ei];
      }
      float aarea = (ax2 - ax1) * (ay2 - ay1);
      if ((km & 1u) && lane > i) {
        float ltx = fmaxf(ax1, b0x1), lty = fmaxf(ay1, b0y1);
        float rbx = fminf(ax2, b0x2), rby = fminf(ay2, b0y2);
        float iw = fmaxf(rbx - ltx, 0.0f);
        float ih = fmaxf(rby - lty, 0.0f);
        float inter = iw * ih;
        float barea = (b0x2 - b0x1) * (b0y2 - b0y1);
        float iou = inter / (aarea + barea - inter + 1e-7f);
        if (iou > IOUT) km &= ~1u;
      }
      for (int q2 = 1; q2 < nq; ++q2) {
        int j = lane + (q2 << 6);
        if (((km >> q2) & 1u) && j > i && j < m) {
          int ej = cgrpL[start + j];
          float jx1 = sx1[ej], jy1 = sy1[ej], jx2 = sx2[ej], jy2 = sy2[ej];
          float ltx = fmaxf(ax1, jx1), lty = fmaxf(ay1, jy1);
          float rbx = fminf(ax2, jx2), rby = fminf(ay2, jy2);
          float iw = fmaxf(rbx - ltx, 0.0f);
          float ih = fmaxf(rby - lty, 0.0f);
          float inter = iw * ih;
          float barea = (jx2 - jx1) * (jy2 - jy1);
          float iou = inter / (aarea + barea - inter + 1e-7f);
          if (iou > IOUT) km &= ~(1u << q2);
        }
      }
    }
    for (int q = 0; q < nq; ++q) {
      int j = lane + (q << 6);
      if (j < m) skp[cgrpL[start + j]] = (unsigned char)((km >> q) & 1u);
    }
  }
  __syncthreads();

  // ---- output compaction (shfl-based scan, 3 barriers) ----
  int kp0 = (int)skp[2 * t];
  int kp1 = (int)skp[2 * t + 1];
  int cnt2 = kp0 + kp1;
  int v2 = cnt2;
  for (int o = 1; o < 64; o <<= 1) { int u2 = __shfl_up(v2, o); if (lane >= o) v2 += u2; }
  if (lane == 63) swsum[w] = v2;
  __syncthreads();
  if (w == 0) {
    int x = (lane < 16) ? swsum[lane] : 0;
    for (int o = 1; o < 16; o <<= 1) { int u2 = __shfl_up(x, o); if (lane >= o) x += u2; }
    if (lane < 16) swsum[lane] = x;   // inclusive wave sums
  }
  __syncthreads();
  int r4 = (w ? swsum[w - 1] : 0) + v2 - cnt2;
  int K = swsum[15];
#pragma unroll
  for (int k = 0; k < 2; ++k) {
    int kp = (k == 0) ? kp0 : kp1;
    if (kp) {
      if (r4 < MAXDET) {
        int j = 2 * t + k;
        float* o = out + ((size_t)b * MAXDET + r4) * 6;
        o[0] = sx1[j]; o[1] = sy1[j]; o[2] = sx2[j]; o[3] = sy2[j];
        o[4] = stop[j];
        o[5] = (float)scls[j];
      }
      ++r4;
    }
  }
  int Kc = K < MAXDET ? K : MAXDET;
  for (int r2 = Kc + t; r2 < MAXDET; r2 += 1024) {
    float* o = out + ((size_t)b * MAXDET + r2) * 6;
    o[0] = 0.0f; o[1] = 0.0f; o[2] = 0.0f; o[3] = 0.0f; o[4] = 0.0f; o[5] = -1.0f;
  }
}

extern "C" void kernel_launch(void* const* d_in, const int* in_sizes, int n_in,
                              void* d_out, int out_size, void* d_ws, size_t ws_size,
                              hipStream_t stream) {
  const float* pred = (const float*)d_in[0];
  float* out = (float*)d_out;

  char* ws = (char*)d_ws;
  size_t off = 0;
  float*              scores = (float*)(ws + off);              off += (size_t)BB * NN * 4;
  uint8_t*            cls    = (uint8_t*)(ws + off);            off += (size_t)BB * NN;
  off = (off + 255) & ~(size_t)255;
  unsigned int*       hist   = (unsigned int*)(ws + off);       off += (size_t)BB * NBIN * 4;
  unsigned int*       gcnt   = (unsigned int*)(ws + off);       off += (size_t)BB * NBIN * 4;
  unsigned int*       gsoff  = (unsigned int*)(ws + off);       off += (size_t)BB * NBIN * 4;
  unsigned long long* gskey  = (unsigned long long*)(ws + off); off += (size_t)BB * SORTN * 8;
  int*                gP     = (int*)(ws + off);                off += (size_t)BB * 4;
  int*                gtot   = (int*)(ws + off);                off += (size_t)BB * 4;
  (void)ws_size; (void)in_sizes; (void)n_in; (void)out_size;

  // hist + gcnt are adjacent: one memset clears both
  hipMemsetAsync(hist, 0, (size_t)BB * NBIN * 4 * 2, stream);
  score_kernel<<<dim3((NN + SROWS - 1) / SROWS, BB), 128, 0, stream>>>(pred, scores, cls, hist);
  scan_kernel<<<BB, 256, 0, stream>>>(hist, gsoff, gP, gtot);
  scatter_kernel<<<dim3((NN + 1023) / 1024, BB), 1024, 0, stream>>>(scores, gsoff, gP, gcnt, gskey);
  final_kernel<<<BB, 1024, 0, stream>>>(pred, cls, gsoff, gcnt, gskey, gtot, out);
}